// Round 20
// baseline (61.642 us; speedup 1.0000x reference)
//
#include <hip/hip_runtime.h>
#include <hip/hip_bf16.h>

// Problem: B=4, S=128, H=768, OUT*TAG=96
// scores[b,i,j,o] = sum_k relu(head[b,i,k] + tail[b,j,k] + b1[k]) * W2[k,o] + b2[o]
// R19: (a) k_pair = R18 memory schedule verbatim + 2-phase compute split
//      (reads->bar->MFMA->bar per K-32 half; pure scheduling fences, no new races).
//      (b) gemm1 = ring-3 counted-vmcnt pipeline (1 barrier/iter, vmcnt(3)).

typedef __bf16 bf16x8 __attribute__((ext_vector_type(8)));
typedef _Float16 f16x8 __attribute__((ext_vector_type(8)));
typedef float f32x4 __attribute__((ext_vector_type(4)));

#define S_   128
#define H_   768
#define K3   2304   // 3*H
#define NOUT 96
#define NIT  36     // K-step-64 iterations

__device__ __forceinline__ unsigned short f2bf(float f) {
    union { __bf16 b; unsigned short u; } c;
    c.b = (__bf16)f;   // RNE
    return c.u;
}

__device__ __forceinline__ unsigned short f2h(float f) {
    union { _Float16 h; unsigned short u; } c;
    c.h = (_Float16)f;
    return c.u;
}

__device__ __forceinline__ void gload_lds16(const unsigned short* g, unsigned short* l) {
    __builtin_amdgcn_global_load_lds(
        (const __attribute__((address_space(1))) void*)g,
        (__attribute__((address_space(3))) void*)l,
        16, 0, 0);
}

// ---------- fused prep: cvt_x | transpose W1 | pack W2 (role by blockIdx.x) ----------
__global__ __launch_bounds__(256) void k_prep(
        const float* __restrict__ x, unsigned short* __restrict__ xb,
        const float* __restrict__ W1, unsigned short* __restrict__ w1t,
        const float* __restrict__ W2, unsigned short* __restrict__ w2f) {
    __shared__ float tile[32][33];
    const int bid = blockIdx.x, tid = threadIdx.x;
    if (bid < 384) {
        int t = bid * 256 + tid;
        float4 v = ((const float4*)x)[t];
        ushort4 o;
        o.x = f2bf(v.x); o.y = f2bf(v.y); o.z = f2bf(v.z); o.w = f2bf(v.w);
        ((ushort4*)xb)[t] = o;
    } else if (bid < 3840) {
        int idx = bid - 384;
        int bx = idx % 72, by = (idx / 72) % 24, bz = idx / 1728;   // 72 x 24 x 2
        const float* src = W1 + (size_t)bz * H_ * K3;
        unsigned short* dst = w1t + (size_t)bz * K3 * H_;
        int c0 = bx * 32, r0 = by * 32;
        int row = tid >> 3, c4 = (tid & 7) * 4;
        float4 v = *(const float4*)(src + (size_t)(r0 + row) * K3 + c0 + c4);
        tile[row][c4 + 0] = v.x; tile[row][c4 + 1] = v.y;
        tile[row][c4 + 2] = v.z; tile[row][c4 + 3] = v.w;
        __syncthreads();
        ushort4 o;
        o.x = f2bf(tile[c4 + 0][row]); o.y = f2bf(tile[c4 + 1][row]);
        o.z = f2bf(tile[c4 + 2][row]); o.w = f2bf(tile[c4 + 3][row]);
        *(ushort4*)(dst + (size_t)(c0 + row) * H_ + r0 + c4) = o;
    } else {
        int t = (bid - 3840) * 256 + tid;   // 27648 exact
        int l = t & 63, f = (t >> 6) % 6, kc = t / 384;
        int k0 = kc * 32 + (l >> 4) * 8;
        int o  = f * 16 + (l & 15);
        unsigned short v[8];
#pragma unroll
        for (int e = 0; e < 8; e++)
            v[e] = f2h(W2[(size_t)(k0 + e) * NOUT + o]);
        *(uint4*)(w2f + (size_t)t * 8) = *(const uint4*)v;
    }
}

// ---------- GEMM1: 64x128 tiles (288 blocks), ring-3 counted-vmcnt pipeline ----------
// head -> headh row-major f16; tail+b1 -> tailsw [32 jbg][36 chunk][8 u][16 row][8 e] f16
__global__ __launch_bounds__(256) void k_gemm1(
        const unsigned short* __restrict__ xb,     // [512][768] bf16
        const unsigned short* __restrict__ w1t,    // [4608][768] bf16
        const float* __restrict__ b1,              // [2304]
        unsigned short* __restrict__ headh,        // [512][2304] f16
        unsigned short* __restrict__ tailsw) {     // chunked tail, f16
    // ring-3 of {A 4KB | B 8KB} = 36KB
    __shared__ __align__(16) unsigned short AB[3][6144];
    const int tid = threadIdx.x;
    const int l = tid & 63, w = tid >> 6;
    const int m0 = blockIdx.y * 64;
    const int n0 = blockIdx.x * 128;
    const int wr = (w >> 1) * 32, wc = (w & 1) * 64;
    const int lr = l & 15, lk = (l >> 4) * 8;
    f32x4 acc[2][4] = {};
    const int NKT = H_ / 32;   // 24

    auto stage = [&](int sbuf, int kt) {
        {   // A: 64x32, 1 x 16B per thread
            int row = tid >> 2, seg = (tid & 3) * 8;
            gload_lds16(xb + (size_t)(m0 + row) * H_ + kt * 32 + seg, &AB[sbuf][tid * 8]);
        }
#pragma unroll
        for (int p = 0; p < 2; ++p) {   // B: 128x32, 2 x 16B per thread
            int idx = p * 256 + tid;
            int row = idx >> 2, seg = (idx & 3) * 8;
            gload_lds16(w1t + (size_t)(n0 + row) * H_ + kt * 32 + seg,
                        &AB[sbuf][2048 + idx * 8]);
        }
    };

    stage(0, 0);
    stage(1, 1);

    for (int n = 0; n < NKT; ++n) {
        // outstanding at top: stage(n+1)[3] (stage(n), issued 2 iters ago, is older).
        asm volatile("s_waitcnt vmcnt(3)" ::: "memory");
        __builtin_amdgcn_s_barrier();
        // stage(n+2): buf (n+2)%3's readers (iter n-1) retired their ds_reads before
        // their MFMAs, which precede this barrier. Clamped dummy keeps counts uniform.
        stage((n + 2) % 3, (n + 2 < NKT) ? (n + 2) : (NKT - 1));

        const unsigned short* Ab = &AB[n % 3][0];
        const unsigned short* Bb = &AB[n % 3][2048];
        bf16x8 af[2], bfr[4];
#pragma unroll
        for (int i = 0; i < 2; i++) af[i]  = *(const bf16x8*)(Ab + (wr + i * 16 + lr) * 32 + lk);
#pragma unroll
        for (int j = 0; j < 4; j++) bfr[j] = *(const bf16x8*)(Bb + (wc + j * 16 + lr) * 32 + lk);
#pragma unroll
        for (int i = 0; i < 2; i++)
#pragma unroll
            for (int j = 0; j < 4; j++)
                acc[i][j] = __builtin_amdgcn_mfma_f32_16x16x32_bf16(af[i], bfr[j], acc[i][j], 0, 0, 0);
    }

    const bool tailblk = (n0 >= K3);
    const int nloc = n0 - (tailblk ? K3 : 0);
    const int lv = (l >> 4) * 4;
    if (!tailblk) {
#pragma unroll
        for (int j = 0; j < 4; j++) {
            int c = nloc + wc + j * 16 + lr;
#pragma unroll
            for (int i = 0; i < 2; i++) {
                int mrow = m0 + wr + i * 16 + lv;
#pragma unroll
                for (int e = 0; e < 4; e++)
                    headh[(size_t)(mrow + e) * K3 + c] = f2h(acc[i][j][e]);
            }
        }
    } else {
#pragma unroll
        for (int j = 0; j < 4; j++) {
            int c = nloc + wc + j * 16 + lr;
            float bias = b1[c];
            int chunk = c >> 6, kin = c & 63, u = kin >> 3, ee = kin & 7;
#pragma unroll
            for (int i = 0; i < 2; i++) {
                int mrow = m0 + wr + i * 16 + lv;
#pragma unroll
                for (int e = 0; e < 4; e++) {
                    int r = mrow + e;                    // global row 0..511
                    int jbg = r >> 4, rr = r & 15;
                    size_t idx = (((size_t)(jbg * 36 + chunk) * 8 + u) * 16 + rr) * 8 + ee;
                    tailsw[idx] = f2h(acc[i][j][e] + bias);
                }
            }
        }
    }
}

// ---------- main pair kernel (R18 memory schedule + 2-phase compute split) ----------
__device__ __forceinline__ f16x8 form8t(uint4 hq, f16x8 t) {
    union { uint4 q; f16x8 v; } H;
    H.q = hq;
    f16x8 s = H.v + t;
    const f16x8 z = {0, 0, 0, 0, 0, 0, 0, 0};
    return __builtin_elementwise_max(s, z);
}

__global__ __launch_bounds__(256) void k_pair(
        const unsigned short* __restrict__ headh,  // [512][2304] f16
        const unsigned short* __restrict__ tailsw, // [32][36][8][16][8] f16
        const unsigned short* __restrict__ w2f,    // [72][6][64][8] f16 frag order
        const float* __restrict__ b2,              // [96]
        float* __restrict__ out) {                 // [4][128][128][96] fp32
    __shared__ __align__(16) unsigned short wlds[4][6144];   // 48KB W2 ring
    __shared__ __align__(16) unsigned short tlds[4][1024];   // 8KB tail ring

    const int tid = threadIdx.x;
    const int w = tid >> 6, l = tid & 63;
    const int lr = l & 15, lkq = l >> 4;
    const int lkoff = lkq * 8;
    const int jb = blockIdx.x;     // 0..7
    const int ig = blockIdx.y;     // 0..15
    const int b  = blockIdx.z;     // 0..3
    const int i0 = ig * 8;

    const unsigned short* Hp   = headh + (size_t)(b * S_ + i0 + 2 * w) * K3;
    const unsigned short* Tsrc = tailsw + (size_t)(b * 8 + jb) * 36 * 1024;

    f32x4 acc[2][6] = {};
    float b2v[6];
#pragma unroll
    for (int f = 0; f < 6; f++) b2v[f] = b2[f * 16 + lr];

    // stage K-64 chunk c into ring sbuf: W2 3 tid-ops + tail 2 l-ops (R18-verbatim)
    auto stage = [&](int sbuf, int c) {
        const unsigned short* wsrc = w2f + (size_t)c * 6144;
#pragma unroll
        for (int i = 0; i < 3; ++i)
            gload_lds16(wsrc + i * 2048 + tid * 8, &wlds[sbuf][i * 2048 + tid * 8]);
        const unsigned short* tsrc = Tsrc + (size_t)c * 1024;
#pragma unroll
        for (int h = 0; h < 2; ++h)
            gload_lds16(tsrc + h * 512 + l * 8, &tlds[sbuf][h * 512 + l * 8]);
    };

    stage(0, 0);
    stage(1, 1);
    // head(0): 4 broadcast loads
    uint4 ha[2], hb[2];
#pragma unroll
    for (int kk = 0; kk < 2; kk++) {
        ha[kk] = *(const uint4*)(Hp + kk * 32 + lkoff);
        hb[kk] = *(const uint4*)(Hp + K3 + kk * 32 + lkoff);
    }

    for (int n = 0; n < NIT; ++n) {
        // R18-verbatim memory schedule
        stage((n + 2) & 3, (n + 2 < NIT) ? (n + 2) : (NIT - 1));
        const int kn = ((n < NIT - 1) ? (n + 1) : n) * 64;
        uint4 han[2], hbn[2];
#pragma unroll
        for (int kk = 0; kk < 2; kk++) {
            han[kk] = *(const uint4*)(Hp + kn + kk * 32 + lkoff);
            hbn[kk] = *(const uint4*)(Hp + K3 + kn + kk * 32 + lkoff);
        }
        // newest 9 = stage(n+2)[5] + head(n+1)[4]; forces stage(n+1)+head(n) done.
        asm volatile("s_waitcnt vmcnt(9)" ::: "memory");
        __builtin_amdgcn_s_barrier();

        const unsigned short* Lb = &wlds[n & 3][0];
        const unsigned short* Tb = &tlds[n & 3][0];
        // 2-phase compute split: {reads -> bar -> MFMA -> bar} per K-32 half.
        // The phase barriers are pure scheduling fences (no buffer hand-off inside
        // the iter crosses them); barrier counts uniform across all waves.
#pragma unroll
        for (int kk = 0; kk < 2; kk++) {
            f16x8 t8 = *(const f16x8*)(Tb + (kk * 4 + lkq) * 128 + lr * 8);
            f16x8 bfr[6];
#pragma unroll
            for (int f = 0; f < 6; f++)
                bfr[f] = *(const f16x8*)(Lb + kk * 3072 + f * 512 + l * 8);
            __builtin_amdgcn_s_barrier();   // end of read region
            f16x8 a0 = form8t(ha[kk], t8);
            f16x8 a1 = form8t(hb[kk], t8);
            __builtin_amdgcn_s_setprio(1);
#pragma unroll
            for (int f = 0; f < 6; f++) {
                acc[0][f] = __builtin_amdgcn_mfma_f32_16x16x32_f16(a0, bfr[f], acc[0][f], 0, 0, 0);
                acc[1][f] = __builtin_amdgcn_mfma_f32_16x16x32_f16(a1, bfr[f], acc[1][f], 0, 0, 0);
            }
            __builtin_amdgcn_s_setprio(0);
            if (kk == 0) __builtin_amdgcn_s_barrier();   // end of MFMA phase 0
        }
#pragma unroll
        for (int kk = 0; kk < 2; kk++) { ha[kk] = han[kk]; hb[kk] = hbn[kk]; }
    }

    float* O = out + (((size_t)(b * S_ + i0 + 2 * w)) * S_ + jb * 16) * NOUT;
#pragma unroll
    for (int q = 0; q < 2; q++)
#pragma unroll
        for (int f = 0; f < 6; f++)
#pragma unroll
            for (int e = 0; e < 4; e++) {
                int j = lkq * 4 + e;
                O[(size_t)q * S_ * NOUT + (size_t)j * NOUT + f * 16 + lr] = acc[q][f][e] + b2v[f];
            }
}

extern "C" void kernel_launch(void* const* d_in, const int* in_sizes, int n_in,
                              void* d_out, int out_size, void* d_ws, size_t ws_size,
                              hipStream_t stream) {
    const float* x  = (const float*)d_in[0];   // [4][128][768]
    const float* W1 = (const float*)d_in[1];   // [1536][2304]
    const float* b1 = (const float*)d_in[2];   // [2304]
    const float* W2 = (const float*)d_in[3];   // [2304][96]
    const float* b2 = (const float*)d_in[4];   // [96]
    float* out = (float*)d_out;

    char* ws = (char*)d_ws;
    unsigned short* xb     = (unsigned short*)(ws);              //  512*768   bf16
    unsigned short* w1t    = (unsigned short*)(ws +   786432);   // 4608*768   bf16
    unsigned short* w2f    = (unsigned short*)(ws +  7864320);   //  72*6*64*8 f16
    unsigned short* headh  = (unsigned short*)(ws +  8306688);   //  512*2304  f16
    unsigned short* tailsw = (unsigned short*)(ws + 10665984);   //  32*36*1024 f16 (2.36MB)
    // total ws use: 13,025,280 bytes

    hipLaunchKernelGGL(k_prep, dim3(3948), dim3(256), 0, stream,
                       x, xb, W1, w1t, W2, w2f);
    hipLaunchKernelGGL(k_gemm1, dim3(36, 8), dim3(256), 0, stream,
                       xb, w1t, b1, headh, tailsw);
    hipLaunchKernelGGL(k_pair, dim3(8, 16, 4), dim3(256), 0, stream,
                       headh, tailsw, w2f, b2, out);
}

// Round 21
// 58.550 us; speedup vs baseline: 1.0528x; 1.0528x over previous
//
#include <hip/hip_runtime.h>
#include <hip/hip_bf16.h>

// Problem: B=4, S=128, H=768, OUT*TAG=96
// scores[b,i,j,o] = sum_k relu(head[b,i,k] + tail[b,j,k] + b1[k]) * W2[k,o] + b2[o]
// R20: k_pair = R18-verbatim (best measured) + start-stagger: second-round blocks
//      ((bid>>8)&1) sleep ~1400 cyc once so the 2 co-resident blocks per CU run
//      phase-offset (one MFMAs while the other reads LDS). gemm1 = R19 ring-3.

typedef __bf16 bf16x8 __attribute__((ext_vector_type(8)));
typedef _Float16 f16x8 __attribute__((ext_vector_type(8)));
typedef float f32x4 __attribute__((ext_vector_type(4)));

#define S_   128
#define H_   768
#define K3   2304   // 3*H
#define NOUT 96
#define NIT  36     // K-step-64 iterations

__device__ __forceinline__ unsigned short f2bf(float f) {
    union { __bf16 b; unsigned short u; } c;
    c.b = (__bf16)f;   // RNE
    return c.u;
}

__device__ __forceinline__ unsigned short f2h(float f) {
    union { _Float16 h; unsigned short u; } c;
    c.h = (_Float16)f;
    return c.u;
}

__device__ __forceinline__ void gload_lds16(const unsigned short* g, unsigned short* l) {
    __builtin_amdgcn_global_load_lds(
        (const __attribute__((address_space(1))) void*)g,
        (__attribute__((address_space(3))) void*)l,
        16, 0, 0);
}

// ---------- fused prep: cvt_x | transpose W1 | pack W2 (role by blockIdx.x) ----------
__global__ __launch_bounds__(256) void k_prep(
        const float* __restrict__ x, unsigned short* __restrict__ xb,
        const float* __restrict__ W1, unsigned short* __restrict__ w1t,
        const float* __restrict__ W2, unsigned short* __restrict__ w2f) {
    __shared__ float tile[32][33];
    const int bid = blockIdx.x, tid = threadIdx.x;
    if (bid < 384) {
        int t = bid * 256 + tid;
        float4 v = ((const float4*)x)[t];
        ushort4 o;
        o.x = f2bf(v.x); o.y = f2bf(v.y); o.z = f2bf(v.z); o.w = f2bf(v.w);
        ((ushort4*)xb)[t] = o;
    } else if (bid < 3840) {
        int idx = bid - 384;
        int bx = idx % 72, by = (idx / 72) % 24, bz = idx / 1728;   // 72 x 24 x 2
        const float* src = W1 + (size_t)bz * H_ * K3;
        unsigned short* dst = w1t + (size_t)bz * K3 * H_;
        int c0 = bx * 32, r0 = by * 32;
        int row = tid >> 3, c4 = (tid & 7) * 4;
        float4 v = *(const float4*)(src + (size_t)(r0 + row) * K3 + c0 + c4);
        tile[row][c4 + 0] = v.x; tile[row][c4 + 1] = v.y;
        tile[row][c4 + 2] = v.z; tile[row][c4 + 3] = v.w;
        __syncthreads();
        ushort4 o;
        o.x = f2bf(tile[c4 + 0][row]); o.y = f2bf(tile[c4 + 1][row]);
        o.z = f2bf(tile[c4 + 2][row]); o.w = f2bf(tile[c4 + 3][row]);
        *(ushort4*)(dst + (size_t)(c0 + row) * H_ + r0 + c4) = o;
    } else {
        int t = (bid - 3840) * 256 + tid;   // 27648 exact
        int l = t & 63, f = (t >> 6) % 6, kc = t / 384;
        int k0 = kc * 32 + (l >> 4) * 8;
        int o  = f * 16 + (l & 15);
        unsigned short v[8];
#pragma unroll
        for (int e = 0; e < 8; e++)
            v[e] = f2h(W2[(size_t)(k0 + e) * NOUT + o]);
        *(uint4*)(w2f + (size_t)t * 8) = *(const uint4*)v;
    }
}

// ---------- GEMM1 (R19-proven): 64x128 tiles, ring-3 counted-vmcnt pipeline ----------
// head -> headh row-major f16; tail+b1 -> tailsw [32 jbg][36 chunk][8 u][16 row][8 e] f16
__global__ __launch_bounds__(256) void k_gemm1(
        const unsigned short* __restrict__ xb,     // [512][768] bf16
        const unsigned short* __restrict__ w1t,    // [4608][768] bf16
        const float* __restrict__ b1,              // [2304]
        unsigned short* __restrict__ headh,        // [512][2304] f16
        unsigned short* __restrict__ tailsw) {     // chunked tail, f16
    __shared__ __align__(16) unsigned short AB[3][6144];   // ring-3 {A 4KB | B 8KB}
    const int tid = threadIdx.x;
    const int l = tid & 63, w = tid >> 6;
    const int m0 = blockIdx.y * 64;
    const int n0 = blockIdx.x * 128;
    const int wr = (w >> 1) * 32, wc = (w & 1) * 64;
    const int lr = l & 15, lk = (l >> 4) * 8;
    f32x4 acc[2][4] = {};
    const int NKT = H_ / 32;   // 24

    auto stage = [&](int sbuf, int kt) {
        {
            int row = tid >> 2, seg = (tid & 3) * 8;
            gload_lds16(xb + (size_t)(m0 + row) * H_ + kt * 32 + seg, &AB[sbuf][tid * 8]);
        }
#pragma unroll
        for (int p = 0; p < 2; ++p) {
            int idx = p * 256 + tid;
            int row = idx >> 2, seg = (idx & 3) * 8;
            gload_lds16(w1t + (size_t)(n0 + row) * H_ + kt * 32 + seg,
                        &AB[sbuf][2048 + idx * 8]);
        }
    };

    stage(0, 0);
    stage(1, 1);

    for (int n = 0; n < NKT; ++n) {
        asm volatile("s_waitcnt vmcnt(3)" ::: "memory");
        __builtin_amdgcn_s_barrier();
        stage((n + 2) % 3, (n + 2 < NKT) ? (n + 2) : (NKT - 1));

        const unsigned short* Ab = &AB[n % 3][0];
        const unsigned short* Bb = &AB[n % 3][2048];
        bf16x8 af[2], bfr[4];
#pragma unroll
        for (int i = 0; i < 2; i++) af[i]  = *(const bf16x8*)(Ab + (wr + i * 16 + lr) * 32 + lk);
#pragma unroll
        for (int j = 0; j < 4; j++) bfr[j] = *(const bf16x8*)(Bb + (wc + j * 16 + lr) * 32 + lk);
#pragma unroll
        for (int i = 0; i < 2; i++)
#pragma unroll
            for (int j = 0; j < 4; j++)
                acc[i][j] = __builtin_amdgcn_mfma_f32_16x16x32_bf16(af[i], bfr[j], acc[i][j], 0, 0, 0);
    }

    const bool tailblk = (n0 >= K3);
    const int nloc = n0 - (tailblk ? K3 : 0);
    const int lv = (l >> 4) * 4;
    if (!tailblk) {
#pragma unroll
        for (int j = 0; j < 4; j++) {
            int c = nloc + wc + j * 16 + lr;
#pragma unroll
            for (int i = 0; i < 2; i++) {
                int mrow = m0 + wr + i * 16 + lv;
#pragma unroll
                for (int e = 0; e < 4; e++)
                    headh[(size_t)(mrow + e) * K3 + c] = f2h(acc[i][j][e]);
            }
        }
    } else {
#pragma unroll
        for (int j = 0; j < 4; j++) {
            int c = nloc + wc + j * 16 + lr;
            float bias = b1[c];
            int chunk = c >> 6, kin = c & 63, u = kin >> 3, ee = kin & 7;
#pragma unroll
            for (int i = 0; i < 2; i++) {
                int mrow = m0 + wr + i * 16 + lv;
#pragma unroll
                for (int e = 0; e < 4; e++) {
                    int r = mrow + e;                    // global row 0..511
                    int jbg = r >> 4, rr = r & 15;
                    size_t idx = (((size_t)(jbg * 36 + chunk) * 8 + u) * 16 + rr) * 8 + ee;
                    tailsw[idx] = f2h(acc[i][j][e] + bias);
                }
            }
        }
    }
}

// ---------- main pair kernel (R18-verbatim + start-stagger) ----------
__device__ __forceinline__ f16x8 form8t(uint4 hq, f16x8 t) {
    union { uint4 q; f16x8 v; } H;
    H.q = hq;
    f16x8 s = H.v + t;
    const f16x8 z = {0, 0, 0, 0, 0, 0, 0, 0};
    return __builtin_elementwise_max(s, z);
}

__global__ __launch_bounds__(256) void k_pair(
        const unsigned short* __restrict__ headh,  // [512][2304] f16
        const unsigned short* __restrict__ tailsw, // [32][36][8][16][8] f16
        const unsigned short* __restrict__ w2f,    // [72][6][64][8] f16 frag order
        const float* __restrict__ b2,              // [96]
        float* __restrict__ out) {                 // [4][128][128][96] fp32
    __shared__ __align__(16) unsigned short wlds[4][6144];   // 48KB W2 ring
    __shared__ __align__(16) unsigned short tlds[4][1024];   // 8KB tail ring

    const int tid = threadIdx.x;
    const int w = tid >> 6, l = tid & 63;
    const int lr = l & 15, lkq = l >> 4;
    const int lkoff = lkq * 8;
    const int jb = blockIdx.x;     // 0..7
    const int ig = blockIdx.y;     // 0..15
    const int b  = blockIdx.z;     // 0..3
    const int i0 = ig * 8;

    // ---- start-stagger: with 512 blocks on 8 XCDs x 32 CUs, CU c of XCD x hosts
    // bids {x+8c, x+8c+256} — the pair differs in bit 8. Offset round-2 blocks by
    // ~half an iteration (~1400 cyc) so the two blocks' phases interleave.
    {
        int bid = jb + ig * 8 + b * 128;
        if ((bid >> 8) & 1) {
            __builtin_amdgcn_s_sleep(11);   // ~704 cyc
            __builtin_amdgcn_s_sleep(11);   // ~1408 total
        }
    }

    const unsigned short* Hp   = headh + (size_t)(b * S_ + i0 + 2 * w) * K3;
    const unsigned short* Tsrc = tailsw + (size_t)(b * 8 + jb) * 36 * 1024;

    f32x4 acc[2][6] = {};
    float b2v[6];
#pragma unroll
    for (int f = 0; f < 6; f++) b2v[f] = b2[f * 16 + lr];

    // stage K-64 chunk c into ring sbuf: W2 3 tid-ops + tail 2 l-ops
    auto stage = [&](int sbuf, int c) {
        const unsigned short* wsrc = w2f + (size_t)c * 6144;
#pragma unroll
        for (int i = 0; i < 3; ++i)
            gload_lds16(wsrc + i * 2048 + tid * 8, &wlds[sbuf][i * 2048 + tid * 8]);
        const unsigned short* tsrc = Tsrc + (size_t)c * 1024;
#pragma unroll
        for (int h = 0; h < 2; ++h)
            gload_lds16(tsrc + h * 512 + l * 8, &tlds[sbuf][h * 512 + l * 8]);
    };

    stage(0, 0);
    stage(1, 1);
    // head(0): 4 broadcast loads
    uint4 ha[2], hb[2];
#pragma unroll
    for (int kk = 0; kk < 2; kk++) {
        ha[kk] = *(const uint4*)(Hp + kk * 32 + lkoff);
        hb[kk] = *(const uint4*)(Hp + K3 + kk * 32 + lkoff);
    }

    for (int n = 0; n < NIT; ++n) {
        // depth-2 staging (dummy clamped re-stage keeps vmcnt uniform)
        stage((n + 2) & 3, (n + 2 < NIT) ? (n + 2) : (NIT - 1));
        // head(n+1) register prefetch (4 loads; clamped on last iter)
        const int kn = ((n < NIT - 1) ? (n + 1) : n) * 64;
        uint4 han[2], hbn[2];
#pragma unroll
        for (int kk = 0; kk < 2; kk++) {
            han[kk] = *(const uint4*)(Hp + kn + kk * 32 + lkoff);
            hbn[kk] = *(const uint4*)(Hp + K3 + kn + kk * 32 + lkoff);
        }

        // newest 9 = stage(n+2)[5] + head(n+1)[4]; forces stage(n+1)+head(n) done.
        asm volatile("s_waitcnt vmcnt(9)" ::: "memory");
        __builtin_amdgcn_s_barrier();

        const unsigned short* Lb = &wlds[n & 3][0];
        const unsigned short* Tb = &tlds[n & 3][0];
        __builtin_amdgcn_s_setprio(1);
#pragma unroll
        for (int kk = 0; kk < 2; kk++) {
            f16x8 t8 = *(const f16x8*)(Tb + (kk * 4 + lkq) * 128 + lr * 8);
            f16x8 a0 = form8t(ha[kk], t8);
            f16x8 a1 = form8t(hb[kk], t8);
#pragma unroll
            for (int f = 0; f < 6; f++) {
                f16x8 bfr = *(const f16x8*)(Lb + kk * 3072 + f * 512 + l * 8);
                acc[0][f] = __builtin_amdgcn_mfma_f32_16x16x32_f16(a0, bfr, acc[0][f], 0, 0, 0);
                acc[1][f] = __builtin_amdgcn_mfma_f32_16x16x32_f16(a1, bfr, acc[1][f], 0, 0, 0);
            }
        }
        __builtin_amdgcn_s_setprio(0);
#pragma unroll
        for (int kk = 0; kk < 2; kk++) { ha[kk] = han[kk]; hb[kk] = hbn[kk]; }
    }

    float* O = out + (((size_t)(b * S_ + i0 + 2 * w)) * S_ + jb * 16) * NOUT;
#pragma unroll
    for (int q = 0; q < 2; q++)
#pragma unroll
        for (int f = 0; f < 6; f++)
#pragma unroll
            for (int e = 0; e < 4; e++) {
                int j = lkq * 4 + e;
                O[(size_t)q * S_ * NOUT + (size_t)j * NOUT + f * 16 + lr] = acc[q][f][e] + b2v[f];
            }
}

extern "C" void kernel_launch(void* const* d_in, const int* in_sizes, int n_in,
                              void* d_out, int out_size, void* d_ws, size_t ws_size,
                              hipStream_t stream) {
    const float* x  = (const float*)d_in[0];   // [4][128][768]
    const float* W1 = (const float*)d_in[1];   // [1536][2304]
    const float* b1 = (const float*)d_in[2];   // [2304]
    const float* W2 = (const float*)d_in[3];   // [2304][96]
    const float* b2 = (const float*)d_in[4];   // [96]
    float* out = (float*)d_out;

    char* ws = (char*)d_ws;
    unsigned short* xb     = (unsigned short*)(ws);              //  512*768   bf16
    unsigned short* w1t    = (unsigned short*)(ws +   786432);   // 4608*768   bf16
    unsigned short* w2f    = (unsigned short*)(ws +  7864320);   //  72*6*64*8 f16
    unsigned short* headh  = (unsigned short*)(ws +  8306688);   //  512*2304  f16
    unsigned short* tailsw = (unsigned short*)(ws + 10665984);   //  32*36*1024 f16 (2.36MB)
    // total ws use: 13,025,280 bytes

    hipLaunchKernelGGL(k_prep, dim3(3948), dim3(256), 0, stream,
                       x, xb, W1, w1t, W2, w2f);
    hipLaunchKernelGGL(k_gemm1, dim3(36, 8), dim3(256), 0, stream,
                       xb, w1t, b1, headh, tailsw);
    hipLaunchKernelGGL(k_pair, dim3(8, 16, 4), dim3(256), 0, stream,
                       headh, tailsw, w2f, b2, out);
}